// Round 6
// baseline (655.521 us; speedup 1.0000x reference)
//
#include <hip/hip_runtime.h>
#include <math.h>

#define HH_ 96
#define WW_ 160
#define HW 15360          // 96*160
#define NPIX 61440        // 4*HW
#define CC 256
#define C0 320            // padded conv0 Cin
#define FF 64
#define H2 192
#define W2 320
#define OHW 61440         // 192*320
#define HO 768
#define WO 1280

typedef __attribute__((ext_vector_type(8))) short short8;
typedef __attribute__((ext_vector_type(4))) float f32x4;

__device__ __forceinline__ float bf2f(ushort u) {
    union { unsigned int i; float f; } v; v.i = ((unsigned int)u) << 16; return v.f;
}
__device__ __forceinline__ ushort f2bf(float f) {
    union { float f; unsigned int i; } v; v.f = f;
    unsigned int u = v.i;
    return (ushort)((u + 0x7FFFu + ((u >> 16) & 1u)) >> 16);
}

// ---------------- fused stats + normalize/LN + NHWC bf16 pack ---------------
__global__ __launch_bounds__(256) void normpack_kernel(
    const float* __restrict__ x1, const float* __restrict__ x2, const float* __restrict__ xt,
    const float* __restrict__ gam, const float* __restrict__ bet,
    ushort* __restrict__ x1c, ushort* __restrict__ x2c,
    ushort* __restrict__ Xhi, ushort* __restrict__ Xlo) {
    __shared__ float tile[32 * 257];
    const int t = threadIdx.x;
    const int pxt = blockIdx.x, which = blockIdx.y, b = blockIdx.z;
    const float* src = (which == 0 ? x1 : which == 1 ? x2 : xt);
    src += (size_t)b * CC * HW + pxt * 32;

    {
        int px_l = t & 31, c_hi = t >> 5;
#pragma unroll 8
        for (int i = 0; i < 32; ++i) {
            int c = i * 8 + c_hi;
            tile[px_l * 257 + c] = src[(size_t)c * HW + px_l];
        }
    }
    __syncthreads();

    const int px = t >> 3, oct = t & 7;
    float s1 = 0.f, s2 = 0.f;
    {
        const float* row = &tile[px * 257];
#pragma unroll
        for (int i = 0; i < 32; ++i) {
            int cc = oct * 32 + ((i + oct * 4) & 31);
            float v = row[cc];
            s1 += v; s2 += v * v;
        }
    }
    s1 += __shfl_xor(s1, 1); s1 += __shfl_xor(s1, 2); s1 += __shfl_xor(s1, 4);
    s2 += __shfl_xor(s2, 1); s2 += __shfl_xor(s2, 2); s2 += __shfl_xor(s2, 4);

    const int p = b * HW + pxt * 32 + px;
    const float* row = &tile[px * 257];
    if (which < 2) {
        float inv = 1.f / fmaxf(sqrtf(s2), 1e-12f);
        ushort* dst = (which == 0 ? x1c : x2c);
        size_t ob = (size_t)p * CC + oct * 32;
#pragma unroll
        for (int g = 0; g < 4; ++g) {
            short8 v;
#pragma unroll
            for (int j = 0; j < 8; ++j)
                v[j] = (short)f2bf(row[oct * 32 + g * 8 + j] * inv);
            *(short8*)(dst + ob + g * 8) = v;
        }
    } else {
        float m = s1 * (1.f / 256.f);
        float var = fmaxf(s2 * (1.f / 256.f) - m * m, 0.f);
        float rs = rsqrtf(var + 1e-5f);
        size_t ob = (size_t)p * C0 + oct * 32;
#pragma unroll
        for (int g = 0; g < 4; ++g) {
            short8 vh, vl;
#pragma unroll
            for (int j = 0; j < 8; ++j) {
                int c = oct * 32 + g * 8 + j;
                float f = (row[c] - m) * rs * gam[c] + bet[c];
                ushort h = f2bf(f);
                vh[j] = (short)h;
                vl[j] = (short)f2bf(f - bf2f(h));
            }
            *(short8*)(Xhi + ob + g * 8) = vh;
            *(short8*)(Xlo + ob + g * 8) = vl;
        }
        short8 z = {0, 0, 0, 0, 0, 0, 0, 0};
        size_t zb = (size_t)p * C0 + 256 + oct * 8;
        *(short8*)(Xhi + zb) = z;
        *(short8*)(Xlo + zb) = z;
    }
}

// ---------------------------------------------------------------- corr ------
__global__ __launch_bounds__(256) void corr_mfma_kernel(
    const ushort* __restrict__ x1c, const ushort* __restrict__ x2c,
    ushort* __restrict__ Xhi, ushort* __restrict__ Xlo) {
    const int lane = threadIdx.x & 63;
    const int wv = threadIdx.x >> 6;
    const int sid = ((blockIdx.x & 7) * 120) + (blockIdx.x >> 3);   // 960 blocks
    const int b  = sid / 240;
    const int rem = sid % 240;
    const int uq = rem / 10, xt = rem % 10;
    const int u = uq * 4 + wv;
    const int x0 = xt * 16;
    const int jl = lane & 15;
    const int kg = lane >> 4;
    const short8 zero8 = {0, 0, 0, 0, 0, 0, 0, 0};

    short8 qf[8];
    {
        size_t qb = ((size_t)b * HW + u * WW_ + x0 + jl) * CC + kg * 8;
#pragma unroll
        for (int ks = 0; ks < 8; ++ks)
            qf[ks] = *(const short8*)(x1c + qb + ks * 32);
    }

    for (int dy = -3; dy <= 3; ++dy) {
        const int y = u + dy;
        if ((unsigned)y >= (unsigned)HH_) continue;
        const int w = u + 2 * dy;
        const bool rowok = (unsigned)w < (unsigned)HH_;

        f32x4 acc0 = (f32x4){0.f, 0.f, 0.f, 0.f};
        f32x4 acc1 = (f32x4){0.f, 0.f, 0.f, 0.f};
        if (rowok) {
#pragma unroll
            for (int nt = 0; nt < 2; ++nt) {
                int kx = x0 - 6 + jl + 16 * nt;
                bool ok = (unsigned)kx < (unsigned)WW_;
                int kxc = min(max(kx, 0), WW_ - 1);
                size_t kb = ((size_t)b * HW + w * WW_ + kxc) * CC + kg * 8;
#pragma unroll
                for (int ks = 0; ks < 8; ++ks) {
                    short8 bv = *(const short8*)(x2c + kb + ks * 32);
                    if (!ok) bv = zero8;
                    if (nt == 0)
                        acc0 = __builtin_amdgcn_mfma_f32_16x16x32_bf16(qf[ks], bv, acc0, 0, 0, 0);
                    else
                        acc1 = __builtin_amdgcn_mfma_f32_16x16x32_bf16(qf[ks], bv, acc1, 0, 0, 0);
                }
            }
        }
#pragma unroll
        for (int nt = 0; nt < 2; ++nt) {
            int j = jl + 16 * nt;
#pragma unroll
            for (int r = 0; r < 4; ++r) {
                int q = kg * 4 + r;
                int tt = j - q - 6;
                if (tt & 1) continue;
                int dx = tt >> 1;
                if (dx < -3 || dx > 3) continue;
                int cx = x0 + q + dx;
                if ((unsigned)cx >= (unsigned)WW_) continue;
                float v = rowok ? (nt == 0 ? acc0[r] : acc1[r]) : 0.f;
                size_t o = ((size_t)(b * HW + y * WW_ + cx)) * C0
                         + 256 + (dy + 3) * 7 + (dx + 3);
                ushort h = f2bf(v);
                Xhi[o] = h;
                Xlo[o] = f2bf(v - bf2f(h));
            }
        }
    }
}

// ------------------------------------------------------------ weight pack ---
__global__ void pack_w_kernel(const float* __restrict__ w, int CinReal, int KC, int isDeconv,
                              ushort* __restrict__ whi, ushort* __restrict__ wlo) {
    int gid = blockIdx.x * blockDim.x + threadIdx.x;
    int total = 9 * KC * 4 * 64;
    if (gid >= total) return;
    int lane = gid & 63;
    int nt = (gid >> 6) & 3;
    int kc = (gid >> 8) % KC;
    int slot = (gid >> 8) / KC;
    int co = nt * 16 + (lane & 15);
    int ky = slot / 3, kx = slot % 3;
    for (int j = 0; j < 8; ++j) {
        int ci = kc * 32 + (lane >> 4) * 8 + j;
        float v = 0.f;
        if (ci < CinReal) {
            if (isDeconv) v = w[((size_t)(ci * 64 + co) * 3 + (2 - ky)) * 3 + (2 - kx)];
            else          v = w[((size_t)(co * CinReal + ci) * 3 + ky) * 3 + kx];
        }
        ushort h = f2bf(v);
        whi[(size_t)gid * 8 + j] = h;
        wlo[(size_t)gid * 8 + j] = f2bf(v - bf2f(h));
    }
}

// ------------------------- MFMA conv core (templated, fully unrolled) -------
// W hi-only; A hi/lo. Block: 4 waves = 4 rows x 32 px window.
template<int KC>
__global__ __launch_bounds__(256, 2) void conv_mfma_t(
    const ushort* __restrict__ Ahi, const ushort* __restrict__ Alo,
    const ushort* __restrict__ Whi,
    const float* __restrict__ bias,
    ushort* __restrict__ Ohi, ushort* __restrict__ Olo,
    const ushort* __restrict__ Rhi, const ushort* __restrict__ Rlo,
    float slope, int act, int hasres) {
    constexpr int CIN = KC * 32;
    const int lane = threadIdx.x & 63;
    const int wave = threadIdx.x >> 6;
    const int kg = lane >> 4;
    const short8 zero8 = {0, 0, 0, 0, 0, 0, 0, 0};

    const int sid = ((blockIdx.x & 7) * 60) + (blockIdx.x >> 3);   // 480 blocks
    const int b0 = sid / 120;
    const int rm = sid % 120;
    const int yq = rm / 5, xw = rm % 5;
    const int y0 = yq * 4 + wave;
    const int x0 = xw * 32;
    const int pmx = x0 + (lane & 15);
    const size_t rowbase = (size_t)b0 * HW;

    f32x4 acc[2][4];
#pragma unroll
    for (int s = 0; s < 2; ++s)
#pragma unroll
        for (int nt = 0; nt < 4; ++nt)
            acc[s][nt] = (f32x4){0.f, 0.f, 0.f, 0.f};

#pragma unroll
    for (int t = 0; t < 9; ++t) {
        const int dy = t / 3 - 1, dx = t % 3 - 1;
        int yy = y0 + dy;
        bool rowok = (unsigned)yy < 96u;
        int yyc = min(max(yy, 0), 95);
        int xx0 = pmx + dx, xx1 = pmx + 16 + dx;
        bool v0 = rowok && (unsigned)xx0 < 160u;
        bool v1 = rowok && (unsigned)xx1 < 160u;
        int xx0c = min(max(xx0, 0), 159), xx1c = min(max(xx1, 0), 159);
        size_t a0 = (rowbase + yyc * WW_ + xx0c) * (size_t)CIN + kg * 8;
        size_t a1 = (rowbase + yyc * WW_ + xx1c) * (size_t)CIN + kg * 8;
        const ushort* wh_t = Whi + (size_t)t * KC * 2048;
#pragma unroll
        for (int kc = 0; kc < KC; ++kc) {
            short8 ah0 = *(const short8*)(Ahi + a0 + kc * 32);
            short8 al0 = *(const short8*)(Alo + a0 + kc * 32);
            short8 ah1 = *(const short8*)(Ahi + a1 + kc * 32);
            short8 al1 = *(const short8*)(Alo + a1 + kc * 32);
            if (!v0) { ah0 = zero8; al0 = zero8; }
            if (!v1) { ah1 = zero8; al1 = zero8; }
#pragma unroll
            for (int nt = 0; nt < 4; ++nt) {
                short8 bh = *(const short8*)(wh_t + (((size_t)kc * 4 + nt) * 64 + lane) * 8);
                acc[0][nt] = __builtin_amdgcn_mfma_f32_16x16x32_bf16(ah0, bh, acc[0][nt], 0, 0, 0);
                acc[1][nt] = __builtin_amdgcn_mfma_f32_16x16x32_bf16(ah1, bh, acc[1][nt], 0, 0, 0);
                acc[0][nt] = __builtin_amdgcn_mfma_f32_16x16x32_bf16(al0, bh, acc[0][nt], 0, 0, 0);
                acc[1][nt] = __builtin_amdgcn_mfma_f32_16x16x32_bf16(al1, bh, acc[1][nt], 0, 0, 0);
            }
        }
    }

#pragma unroll
    for (int s = 0; s < 2; ++s) {
#pragma unroll
        for (int r = 0; r < 4; ++r) {
            size_t pr = rowbase + y0 * WW_ + x0 + s * 16 + kg * 4 + r;
#pragma unroll
            for (int nt = 0; nt < 4; ++nt) {
                int co = nt * 16 + (lane & 15);
                float vv = acc[s][nt][r] + bias[co];
                size_t oo = pr * 64 + co;
                if (hasres) vv += bf2f(Rhi[oo]) + bf2f(Rlo[oo]);
                if (act) vv = vv >= 0.f ? vv : vv * slope;
                ushort h = f2bf(vv);
                Ohi[oo] = h;
                Olo[oo] = f2bf(vv - bf2f(h));
            }
        }
    }
}

// ------------------------------------------- fused transposed conv (4 par) --
// W hi-only; writes f32 dec.
__global__ __launch_bounds__(256, 2) void deconv_fused_kernel(
    const ushort* __restrict__ Ahi, const ushort* __restrict__ Alo,
    const ushort* __restrict__ Whi,
    const float* __restrict__ bias,
    float* __restrict__ dec) {
    const int lane = threadIdx.x & 63;
    const int wave = threadIdx.x >> 6;
    const int kg = lane >> 4;
    const short8 zero8 = {0, 0, 0, 0, 0, 0, 0, 0};

    const int sid = ((blockIdx.x & 7) * 120) + (blockIdx.x >> 3);   // 960 blocks
    const int b0 = sid / 240;
    const int rm = sid % 240;
    const int yq = rm / 10, xh = rm % 10;
    const int y0 = yq * 4 + wave;
    const int x0 = xh * 16;
    const size_t rowbase = (size_t)b0 * HW;

    f32x4 acc[4][4];   // [parity][nt]
#pragma unroll
    for (int p = 0; p < 4; ++p)
#pragma unroll
        for (int nt = 0; nt < 4; ++nt) acc[p][nt] = (f32x4){0.f, 0.f, 0.f, 0.f};

    const int nuse[4]   = {4, 2, 2, 1};
    const int upar[4][4] = {{0, 1, 2, 3}, {1, 3, -1, -1}, {2, 3, -1, -1}, {3, -1, -1, -1}};
    const int uslt[4][4] = {{4, 3, 1, 0}, {5, 2, -1, -1}, {7, 6, -1, -1}, {8, -1, -1, -1}};

#pragma unroll
    for (int o = 0; o < 4; ++o) {
        const int ody = o >> 1, odx = o & 1;
        int yy = y0 + ody, xx = x0 + (lane & 15) + odx;
        bool v = (unsigned)yy < 96u && (unsigned)xx < 160u;
        int yyc = min(yy, 95), xxc = min(xx, 159);
        size_t a = (rowbase + yyc * WW_ + xxc) * 64 + kg * 8;
#pragma unroll
        for (int kc = 0; kc < 2; ++kc) {
            short8 ah = *(const short8*)(Ahi + a + kc * 32);
            short8 al = *(const short8*)(Alo + a + kc * 32);
            if (!v) { ah = zero8; al = zero8; }
#pragma unroll
            for (int u = 0; u < 4; ++u) {
                if (u >= nuse[o]) break;
                int par = upar[o][u], slot = uslt[o][u];
#pragma unroll
                for (int nt = 0; nt < 4; ++nt) {
                    short8 bh = *(const short8*)(Whi + ((size_t)slot * 2 + kc) * 2048
                                                 + ((size_t)nt * 64 + lane) * 8);
                    acc[par][nt] = __builtin_amdgcn_mfma_f32_16x16x32_bf16(ah, bh, acc[par][nt], 0, 0, 0);
                    acc[par][nt] = __builtin_amdgcn_mfma_f32_16x16x32_bf16(al, bh, acc[par][nt], 0, 0, 0);
                }
            }
        }
    }

#pragma unroll
    for (int r = 0; r < 4; ++r) {
        int x2 = x0 + kg * 4 + r;
#pragma unroll
        for (int par = 0; par < 4; ++par) {
            int py = par >> 1, px = par & 1;
            size_t po = ((size_t)b0 * H2 + 2 * y0 + py) * W2 + 2 * x2 + px;
#pragma unroll
            for (int nt = 0; nt < 4; ++nt) {
                int co = nt * 16 + (lane & 15);
                dec[po * 64 + co] = acc[par][nt][r] + bias[co];
            }
        }
    }
}

// ---------------------------------------------------------------- flow ------
__global__ __launch_bounds__(256) void flow_kernel(const float* __restrict__ dec,
                                                   const float* __restrict__ wf,
                                                   const float* __restrict__ bf2v,
                                                   float* __restrict__ flow) {
    __shared__ float wsm[1152];
    for (int i = threadIdx.x; i < 1152; i += 256) wsm[i] = wf[i];
    __syncthreads();
    int fid = ((blockIdx.x & 7) * 120) + (blockIdx.x >> 3);   // 960 blocks
    int p = fid * 256 + threadIdx.x;
    if (p >= 4 * OHW) return;
    int b = p / OHW, rem = p % OHW, oy = rem / W2, ox = rem % W2;
    float a0 = bf2v[0], a1 = bf2v[1];
    for (int ky = 0; ky < 3; ++ky) {
        int yy = oy + ky - 1;
        if ((unsigned)yy >= (unsigned)H2) continue;
        for (int kx = 0; kx < 3; ++kx) {
            int xx = ox + kx - 1;
            if ((unsigned)xx >= (unsigned)W2) continue;
            size_t base = ((size_t)b * OHW + yy * W2 + xx) * 64;
            int tap = ky * 3 + kx;
#pragma unroll
            for (int c4 = 0; c4 < 16; ++c4) {
                f32x4 v = *(const f32x4*)(dec + base + c4 * 4);
#pragma unroll
                for (int j = 0; j < 4; ++j) {
                    int ci = c4 * 4 + j;
                    a0 += v[j] * wsm[ci * 9 + tap];
                    a1 += v[j] * wsm[(64 + ci) * 9 + tap];
                }
            }
        }
    }
    flow[(size_t)(b * 2 + 0) * OHW + rem] = a0;
    flow[(size_t)(b * 2 + 1) * OHW + rem] = a1;
}

// --------------------------------------------------------------- resize -----
__global__ void resize_kernel(const float* __restrict__ flow, float* __restrict__ out) {
    int idx = blockIdx.x * blockDim.x + threadIdx.x;
    int total = 4 * 2 * HO * WO;
    if (idx >= total) return;
    int ox = idx % WO;
    int oy = (idx / WO) % HO;
    int c = (idx / (WO * HO)) % 2;
    int b = idx / (WO * HO * 2);
    float sy = (oy + 0.5f) * 0.25f - 0.5f;
    float sx = (ox + 0.5f) * 0.25f - 0.5f;
    int y0 = (int)floorf(sy);
    int x0 = (int)floorf(sx);
    float fy = sy - y0;
    float fx = sx - x0;
    int y0c = min(max(y0, 0), H2 - 1);
    int y1c = min(max(y0 + 1, 0), H2 - 1);
    int x0c = min(max(x0, 0), W2 - 1);
    int x1c = min(max(x0 + 1, 0), W2 - 1);
    const float* fb = flow + (size_t)(b * 2 + c) * OHW;
    float v00 = fb[y0c * W2 + x0c];
    float v01 = fb[y0c * W2 + x1c];
    float v10 = fb[y1c * W2 + x0c];
    float v11 = fb[y1c * W2 + x1c];
    float v = (1.f - fy) * ((1.f - fx) * v00 + fx * v01)
            + fy * ((1.f - fx) * v10 + fx * v11);
    out[idx] = v * 4.0f;
}

// =================================================================== host ===
extern "C" void kernel_launch(void* const* d_in, const int* in_sizes, int n_in,
                              void* d_out, int out_size, void* d_ws, size_t ws_size,
                              hipStream_t stream) {
    const float* x1   = (const float*)d_in[0];
    const float* x2   = (const float*)d_in[1];
    const float* xt   = (const float*)d_in[2];
    const float* gln  = (const float*)d_in[3];
    const float* bln  = (const float*)d_in[4];
    const float* w0   = (const float*)d_in[5];
    const float* b0   = (const float*)d_in[6];
    const float* wr1  = (const float*)d_in[7];
    const float* br1  = (const float*)d_in[8];
    const float* wr2  = (const float*)d_in[9];
    const float* br2  = (const float*)d_in[10];
    const float* w2   = (const float*)d_in[11];
    const float* b2   = (const float*)d_in[12];
    const float* w3   = (const float*)d_in[13];
    const float* b3   = (const float*)d_in[14];
    const float* wdec = (const float*)d_in[15];
    const float* bdec = (const float*)d_in[16];
    const float* wf   = (const float*)d_in[17];
    const float* bfv  = (const float*)d_in[18];
    float* out = (float*)d_out;

    char* ws = (char*)d_ws;
    ushort* x1c   = (ushort*)(ws + 1048576);
    ushort* x2c   = (ushort*)(ws + 1048576 + 31457280);
    ushort* X0hi  = (ushort*)(ws + 67108864);
    ushort* X0lo  = (ushort*)(ws + 106430464);
    const size_t P = 7864320;
    ushort* y0hi = (ushort*)(ws + 1048576 + 0 * P);
    ushort* y0lo = (ushort*)(ws + 1048576 + 1 * P);
    ushort* t1hi = (ushort*)(ws + 1048576 + 2 * P);
    ushort* t1lo = (ushort*)(ws + 1048576 + 3 * P);
    ushort* t2hi = (ushort*)(ws + 1048576 + 4 * P);
    ushort* t2lo = (ushort*)(ws + 1048576 + 5 * P);
    float*  dec  = (float*)(ws + 67108864);      // 62,914,560 B (f32)
    float*  flowb = (float*)(ws + 130023424);
    char* wp = ws + 146800640;
    ushort* W0hi  = (ushort*)(wp);             ushort* W0lo  = (ushort*)(wp + 368640);
    ushort* WR1hi = (ushort*)(wp + 737280);    ushort* WR1lo = (ushort*)(wp + 737280 + 73728);
    ushort* WR2hi = (ushort*)(wp + 884736);    ushort* WR2lo = (ushort*)(wp + 884736 + 73728);
    ushort* W2hi  = (ushort*)(wp + 1032192);   ushort* W2lo  = (ushort*)(wp + 1032192 + 73728);
    ushort* W3hi  = (ushort*)(wp + 1179648);   ushort* W3lo  = (ushort*)(wp + 1179648 + 73728);
    ushort* WDhi  = (ushort*)(wp + 1327104);   ushort* WDlo  = (ushort*)(wp + 1327104 + 73728);

    pack_w_kernel<<<90, 256, 0, stream>>>(w0, 305, 10, 0, W0hi, W0lo);
    pack_w_kernel<<<18, 256, 0, stream>>>(wr1, 64, 2, 0, WR1hi, WR1lo);
    pack_w_kernel<<<18, 256, 0, stream>>>(wr2, 64, 2, 0, WR2hi, WR2lo);
    pack_w_kernel<<<18, 256, 0, stream>>>(w2, 64, 2, 0, W2hi, W2lo);
    pack_w_kernel<<<18, 256, 0, stream>>>(w3, 64, 2, 0, W3hi, W3lo);
    pack_w_kernel<<<18, 256, 0, stream>>>(wdec, 64, 2, 1, WDhi, WDlo);

    normpack_kernel<<<dim3(480, 3, 4), 256, 0, stream>>>(
        x1, x2, xt, gln, bln, x1c, x2c, X0hi, X0lo);
    corr_mfma_kernel<<<960, 256, 0, stream>>>(x1c, x2c, X0hi, X0lo);

    conv_mfma_t<10><<<480, 256, 0, stream>>>(X0hi, X0lo, W0hi, b0,
        y0hi, y0lo, nullptr, nullptr, 0.f, 0, 0);
    conv_mfma_t<2><<<480, 256, 0, stream>>>(y0hi, y0lo, WR1hi, br1,
        t1hi, t1lo, nullptr, nullptr, 0.1f, 1, 0);
    conv_mfma_t<2><<<480, 256, 0, stream>>>(t1hi, t1lo, WR2hi, br2,
        t2hi, t2lo, y0hi, y0lo, 0.1f, 1, 1);
    conv_mfma_t<2><<<480, 256, 0, stream>>>(t2hi, t2lo, W2hi, b2,
        t1hi, t1lo, nullptr, nullptr, 0.2f, 1, 0);
    conv_mfma_t<2><<<480, 256, 0, stream>>>(t1hi, t1lo, W3hi, b3,
        t2hi, t2lo, nullptr, nullptr, 0.2f, 1, 0);
    deconv_fused_kernel<<<960, 256, 0, stream>>>(t2hi, t2lo, WDhi, bdec, dec);

    flow_kernel<<<960, 256, 0, stream>>>(dec, wf, bfv, flowb);
    resize_kernel<<<30720, 256, 0, stream>>>(flowb, out);

    (void)in_sizes; (void)n_in; (void)out_size; (void)ws_size;
}

// Round 7
// 501.270 us; speedup vs baseline: 1.3077x; 1.3077x over previous
//
#include <hip/hip_runtime.h>
#include <math.h>

#define HH_ 96
#define WW_ 160
#define HW 15360          // 96*160
#define NPIX 61440        // 4*HW
#define CC 256
#define C0 320            // padded conv0 Cin
#define FF 64
#define H2 192
#define W2 320
#define OHW 61440         // 192*320
#define HO 768
#define WO 1280

typedef __attribute__((ext_vector_type(8))) short short8;
typedef __attribute__((ext_vector_type(4))) float f32x4;

__device__ __forceinline__ float bf2f(ushort u) {
    union { unsigned int i; float f; } v; v.i = ((unsigned int)u) << 16; return v.f;
}
__device__ __forceinline__ ushort f2bf(float f) {
    union { float f; unsigned int i; } v; v.f = f;
    unsigned int u = v.i;
    return (ushort)((u + 0x7FFFu + ((u >> 16) & 1u)) >> 16);
}

// ---------------- fused stats + normalize/LN + NHWC bf16 pack ---------------
__global__ __launch_bounds__(256) void normpack_kernel(
    const float* __restrict__ x1, const float* __restrict__ x2, const float* __restrict__ xt,
    const float* __restrict__ gam, const float* __restrict__ bet,
    ushort* __restrict__ x1c, ushort* __restrict__ x2c,
    ushort* __restrict__ Xhi, ushort* __restrict__ Xlo) {
    __shared__ float tile[32 * 257];
    const int t = threadIdx.x;
    const int pxt = blockIdx.x, which = blockIdx.y, b = blockIdx.z;
    const float* src = (which == 0 ? x1 : which == 1 ? x2 : xt);
    src += (size_t)b * CC * HW + pxt * 32;

    {
        int px_l = t & 31, c_hi = t >> 5;
#pragma unroll 8
        for (int i = 0; i < 32; ++i) {
            int c = i * 8 + c_hi;
            tile[px_l * 257 + c] = src[(size_t)c * HW + px_l];
        }
    }
    __syncthreads();

    const int px = t >> 3, oct = t & 7;
    float s1 = 0.f, s2 = 0.f;
    {
        const float* row = &tile[px * 257];
#pragma unroll
        for (int i = 0; i < 32; ++i) {
            int cc = oct * 32 + ((i + oct * 4) & 31);
            float v = row[cc];
            s1 += v; s2 += v * v;
        }
    }
    s1 += __shfl_xor(s1, 1); s1 += __shfl_xor(s1, 2); s1 += __shfl_xor(s1, 4);
    s2 += __shfl_xor(s2, 1); s2 += __shfl_xor(s2, 2); s2 += __shfl_xor(s2, 4);

    const int p = b * HW + pxt * 32 + px;
    const float* row = &tile[px * 257];
    if (which < 2) {
        float inv = 1.f / fmaxf(sqrtf(s2), 1e-12f);
        ushort* dst = (which == 0 ? x1c : x2c);
        size_t ob = (size_t)p * CC + oct * 32;
#pragma unroll
        for (int g = 0; g < 4; ++g) {
            short8 v;
#pragma unroll
            for (int j = 0; j < 8; ++j)
                v[j] = (short)f2bf(row[oct * 32 + g * 8 + j] * inv);
            *(short8*)(dst + ob + g * 8) = v;
        }
    } else {
        float m = s1 * (1.f / 256.f);
        float var = fmaxf(s2 * (1.f / 256.f) - m * m, 0.f);
        float rs = rsqrtf(var + 1e-5f);
        size_t ob = (size_t)p * C0 + oct * 32;
#pragma unroll
        for (int g = 0; g < 4; ++g) {
            short8 vh, vl;
#pragma unroll
            for (int j = 0; j < 8; ++j) {
                int c = oct * 32 + g * 8 + j;
                float f = (row[c] - m) * rs * gam[c] + bet[c];
                ushort h = f2bf(f);
                vh[j] = (short)h;
                vl[j] = (short)f2bf(f - bf2f(h));
            }
            *(short8*)(Xhi + ob + g * 8) = vh;
            *(short8*)(Xlo + ob + g * 8) = vl;
        }
        short8 z = {0, 0, 0, 0, 0, 0, 0, 0};
        size_t zb = (size_t)p * C0 + 256 + oct * 8;
        *(short8*)(Xhi + zb) = z;
        *(short8*)(Xlo + zb) = z;
    }
}

// ---------------------------------------------------------------- corr ------
__global__ __launch_bounds__(256) void corr_mfma_kernel(
    const ushort* __restrict__ x1c, const ushort* __restrict__ x2c,
    ushort* __restrict__ Xhi, ushort* __restrict__ Xlo) {
    const int lane = threadIdx.x & 63;
    const int wv = threadIdx.x >> 6;
    const int sid = ((blockIdx.x & 7) * 120) + (blockIdx.x >> 3);   // 960 blocks
    const int b  = sid / 240;
    const int rem = sid % 240;
    const int uq = rem / 10, xt = rem % 10;
    const int u = uq * 4 + wv;
    const int x0 = xt * 16;
    const int jl = lane & 15;
    const int kg = lane >> 4;
    const short8 zero8 = {0, 0, 0, 0, 0, 0, 0, 0};

    short8 qf[8];
    {
        size_t qb = ((size_t)b * HW + u * WW_ + x0 + jl) * CC + kg * 8;
#pragma unroll
        for (int ks = 0; ks < 8; ++ks)
            qf[ks] = *(const short8*)(x1c + qb + ks * 32);
    }

    for (int dy = -3; dy <= 3; ++dy) {
        const int y = u + dy;
        if ((unsigned)y >= (unsigned)HH_) continue;
        const int w = u + 2 * dy;
        const bool rowok = (unsigned)w < (unsigned)HH_;

        f32x4 acc0 = (f32x4){0.f, 0.f, 0.f, 0.f};
        f32x4 acc1 = (f32x4){0.f, 0.f, 0.f, 0.f};
        if (rowok) {
#pragma unroll
            for (int nt = 0; nt < 2; ++nt) {
                int kx = x0 - 6 + jl + 16 * nt;
                bool ok = (unsigned)kx < (unsigned)WW_;
                int kxc = min(max(kx, 0), WW_ - 1);
                size_t kb = ((size_t)b * HW + w * WW_ + kxc) * CC + kg * 8;
#pragma unroll
                for (int ks = 0; ks < 8; ++ks) {
                    short8 bv = *(const short8*)(x2c + kb + ks * 32);
                    if (!ok) bv = zero8;
                    if (nt == 0)
                        acc0 = __builtin_amdgcn_mfma_f32_16x16x32_bf16(qf[ks], bv, acc0, 0, 0, 0);
                    else
                        acc1 = __builtin_amdgcn_mfma_f32_16x16x32_bf16(qf[ks], bv, acc1, 0, 0, 0);
                }
            }
        }
#pragma unroll
        for (int nt = 0; nt < 2; ++nt) {
            int j = jl + 16 * nt;
#pragma unroll
            for (int r = 0; r < 4; ++r) {
                int q = kg * 4 + r;
                int tt = j - q - 6;
                if (tt & 1) continue;
                int dx = tt >> 1;
                if (dx < -3 || dx > 3) continue;
                int cx = x0 + q + dx;
                if ((unsigned)cx >= (unsigned)WW_) continue;
                float v = rowok ? (nt == 0 ? acc0[r] : acc1[r]) : 0.f;
                size_t o = ((size_t)(b * HW + y * WW_ + cx)) * C0
                         + 256 + (dy + 3) * 7 + (dx + 3);
                ushort h = f2bf(v);
                Xhi[o] = h;
                Xlo[o] = f2bf(v - bf2f(h));
            }
        }
    }
}

// ------------------------------------------------------------ weight pack ---
__global__ void pack_w_kernel(const float* __restrict__ w, int CinReal, int KC, int isDeconv,
                              ushort* __restrict__ whi, ushort* __restrict__ wlo) {
    int gid = blockIdx.x * blockDim.x + threadIdx.x;
    int total = 9 * KC * 4 * 64;
    if (gid >= total) return;
    int lane = gid & 63;
    int nt = (gid >> 6) & 3;
    int kc = (gid >> 8) % KC;
    int slot = (gid >> 8) / KC;
    int co = nt * 16 + (lane & 15);
    int ky = slot / 3, kx = slot % 3;
    for (int j = 0; j < 8; ++j) {
        int ci = kc * 32 + (lane >> 4) * 8 + j;
        float v = 0.f;
        if (ci < CinReal) {
            if (isDeconv) v = w[((size_t)(ci * 64 + co) * 3 + (2 - ky)) * 3 + (2 - kx)];
            else          v = w[((size_t)(co * CinReal + ci) * 3 + ky) * 3 + kx];
        }
        ushort h = f2bf(v);
        whi[(size_t)gid * 8 + j] = h;
        wlo[(size_t)gid * 8 + j] = f2bf(v - bf2f(h));
    }
}

// --------------- MFMA conv core: LDS-staged, double-buffered ----------------
// LDS chunk layout (ushort idx): buf[2] x plane[2] x kg[4] x row[6] x px[34] x ch[8]
//   kg stride 1640 (pad +8 for bank spread), plane stride 6560, buf stride 13120.
// Block: 4 waves = rows yq*4..+3, px window x0..x0+31. W VGPR-stationary.
template<int KC>
__global__ __launch_bounds__(256, 2) void conv_lds_t(
    const ushort* __restrict__ Ahi, const ushort* __restrict__ Alo,
    const ushort* __restrict__ Whi,
    const float* __restrict__ bias,
    ushort* __restrict__ Ohi, ushort* __restrict__ Olo,
    const ushort* __restrict__ Rhi, const ushort* __restrict__ Rlo,
    float slope, int act, int hasres) {
    constexpr int CIN = KC * 32;
    __shared__ ushort lds[2 * 13120];
    const int t = threadIdx.x;
    const int lane = t & 63;
    const int wave = t >> 6;
    const int kg = lane >> 4;
    const int jl = lane & 15;
    const short8 zero8 = {0, 0, 0, 0, 0, 0, 0, 0};

    const int sid = ((blockIdx.x & 7) * 60) + (blockIdx.x >> 3);   // 480 blocks
    const int b0 = sid / 120;
    const int rm = sid % 120;
    const int yq = rm / 5, xw = rm % 5;
    const int y0 = yq * 4;           // wave handles row y0+wave
    const int x0 = xw * 32;
    const size_t rowbase = (size_t)b0 * HW;

    f32x4 acc[2][4];
#pragma unroll
    for (int s = 0; s < 2; ++s)
#pragma unroll
        for (int nt = 0; nt < 4; ++nt)
            acc[s][nt] = (f32x4){0.f, 0.f, 0.f, 0.f};

    // ---- staging: 816 = 6 rows x 34 px x 4 kg elements per plane ----
    auto stage = [&](ushort* buf, int kc) {
#pragma unroll
        for (int i = 0; i < 4; ++i) {
            int e = t + i * 256;
            if (e < 816) {
                int kge = e & 3;
                int q = e >> 2;
                int pe = q % 34;
                int re = q / 34;
                int gy = y0 - 1 + re, gx = x0 - 1 + pe;
                bool ok = ((unsigned)gy < 96u) && ((unsigned)gx < 160u);
                short8 vh = zero8, vl = zero8;
                if (ok) {
                    size_t ga = ((rowbase + gy * WW_ + gx) * (size_t)CIN) + kc * 32 + kge * 8;
                    vh = *(const short8*)(Ahi + ga);
                    vl = *(const short8*)(Alo + ga);
                }
                int lo = kge * 1640 + (re * 34 + pe) * 8;
                *(short8*)(buf + lo) = vh;
                *(short8*)(buf + 6560 + lo) = vl;
            }
        }
    };

    stage(lds, 0);

#pragma unroll 1
    for (int kc = 0; kc < KC; ++kc) {
        __syncthreads();
        if (kc + 1 < KC) stage(lds + ((kc + 1) & 1) * 13120, kc + 1);
        const ushort* bufc = lds + (kc & 1) * 13120;
#pragma unroll
        for (int tap = 0; tap < 9; ++tap) {
            const int dy = tap / 3 - 1, dx = tap % 3 - 1;
            const int abase = kg * 1640 + (wave + dy + 1) * 272 + (jl + dx + 1) * 8;
            short8 ah0 = *(const short8*)(bufc + abase);
            short8 ah1 = *(const short8*)(bufc + abase + 128);
            short8 al0 = *(const short8*)(bufc + 6560 + abase);
            short8 al1 = *(const short8*)(bufc + 6560 + abase + 128);
            const ushort* wt = Whi + (size_t)(tap * KC + kc) * 2048;
#pragma unroll
            for (int nt = 0; nt < 4; ++nt) {
                short8 bh = *(const short8*)(wt + (nt * 64 + lane) * 8);
                acc[0][nt] = __builtin_amdgcn_mfma_f32_16x16x32_bf16(ah0, bh, acc[0][nt], 0, 0, 0);
                acc[1][nt] = __builtin_amdgcn_mfma_f32_16x16x32_bf16(ah1, bh, acc[1][nt], 0, 0, 0);
                acc[0][nt] = __builtin_amdgcn_mfma_f32_16x16x32_bf16(al0, bh, acc[0][nt], 0, 0, 0);
                acc[1][nt] = __builtin_amdgcn_mfma_f32_16x16x32_bf16(al1, bh, acc[1][nt], 0, 0, 0);
            }
        }
    }

#pragma unroll
    for (int s = 0; s < 2; ++s) {
#pragma unroll
        for (int r = 0; r < 4; ++r) {
            size_t pr = rowbase + (y0 + wave) * WW_ + x0 + s * 16 + kg * 4 + r;
#pragma unroll
            for (int nt = 0; nt < 4; ++nt) {
                int co = nt * 16 + jl;
                float vv = acc[s][nt][r] + bias[co];
                size_t oo = pr * 64 + co;
                if (hasres) vv += bf2f(Rhi[oo]) + bf2f(Rlo[oo]);
                if (act) vv = vv >= 0.f ? vv : vv * slope;
                ushort h = f2bf(vv);
                Ohi[oo] = h;
                Olo[oo] = f2bf(vv - bf2f(h));
            }
        }
    }
}

// ------------------------------------------- fused transposed conv (4 par) --
__global__ __launch_bounds__(256, 2) void deconv_fused_kernel(
    const ushort* __restrict__ Ahi, const ushort* __restrict__ Alo,
    const ushort* __restrict__ Whi,
    const float* __restrict__ bias,
    float* __restrict__ dec) {
    const int lane = threadIdx.x & 63;
    const int wave = threadIdx.x >> 6;
    const int kg = lane >> 4;
    const short8 zero8 = {0, 0, 0, 0, 0, 0, 0, 0};

    const int sid = ((blockIdx.x & 7) * 120) + (blockIdx.x >> 3);   // 960 blocks
    const int b0 = sid / 240;
    const int rm = sid % 240;
    const int yq = rm / 10, xh = rm % 10;
    const int y0 = yq * 4 + wave;
    const int x0 = xh * 16;
    const size_t rowbase = (size_t)b0 * HW;

    f32x4 acc[4][4];   // [parity][nt]
#pragma unroll
    for (int p = 0; p < 4; ++p)
#pragma unroll
        for (int nt = 0; nt < 4; ++nt) acc[p][nt] = (f32x4){0.f, 0.f, 0.f, 0.f};

    const int nuse[4]   = {4, 2, 2, 1};
    const int upar[4][4] = {{0, 1, 2, 3}, {1, 3, -1, -1}, {2, 3, -1, -1}, {3, -1, -1, -1}};
    const int uslt[4][4] = {{4, 3, 1, 0}, {5, 2, -1, -1}, {7, 6, -1, -1}, {8, -1, -1, -1}};

#pragma unroll
    for (int o = 0; o < 4; ++o) {
        const int ody = o >> 1, odx = o & 1;
        int yy = y0 + ody, xx = x0 + (lane & 15) + odx;
        bool v = (unsigned)yy < 96u && (unsigned)xx < 160u;
        int yyc = min(yy, 95), xxc = min(xx, 159);
        size_t a = (rowbase + yyc * WW_ + xxc) * 64 + kg * 8;
#pragma unroll
        for (int kc = 0; kc < 2; ++kc) {
            short8 ah = *(const short8*)(Ahi + a + kc * 32);
            short8 al = *(const short8*)(Alo + a + kc * 32);
            if (!v) { ah = zero8; al = zero8; }
#pragma unroll
            for (int u = 0; u < 4; ++u) {
                if (u >= nuse[o]) break;
                int par = upar[o][u], slot = uslt[o][u];
#pragma unroll
                for (int nt = 0; nt < 4; ++nt) {
                    short8 bh = *(const short8*)(Whi + ((size_t)slot * 2 + kc) * 2048
                                                 + ((size_t)nt * 64 + lane) * 8);
                    acc[par][nt] = __builtin_amdgcn_mfma_f32_16x16x32_bf16(ah, bh, acc[par][nt], 0, 0, 0);
                    acc[par][nt] = __builtin_amdgcn_mfma_f32_16x16x32_bf16(al, bh, acc[par][nt], 0, 0, 0);
                }
            }
        }
    }

#pragma unroll
    for (int r = 0; r < 4; ++r) {
        int x2 = x0 + kg * 4 + r;
#pragma unroll
        for (int par = 0; par < 4; ++par) {
            int py = par >> 1, px = par & 1;
            size_t po = ((size_t)b0 * H2 + 2 * y0 + py) * W2 + 2 * x2 + px;
#pragma unroll
            for (int nt = 0; nt < 4; ++nt) {
                int co = nt * 16 + (lane & 15);
                dec[po * 64 + co] = acc[par][nt][r] + bias[co];
            }
        }
    }
}

// ---------------------------------------------------------------- flow ------
__global__ __launch_bounds__(256) void flow_kernel(const float* __restrict__ dec,
                                                   const float* __restrict__ wf,
                                                   const float* __restrict__ bf2v,
                                                   float* __restrict__ flow) {
    __shared__ float wsm[1152];
    for (int i = threadIdx.x; i < 1152; i += 256) wsm[i] = wf[i];
    __syncthreads();
    int fid = ((blockIdx.x & 7) * 120) + (blockIdx.x >> 3);   // 960 blocks
    int p = fid * 256 + threadIdx.x;
    if (p >= 4 * OHW) return;
    int b = p / OHW, rem = p % OHW, oy = rem / W2, ox = rem % W2;
    float a0 = bf2v[0], a1 = bf2v[1];
    for (int ky = 0; ky < 3; ++ky) {
        int yy = oy + ky - 1;
        if ((unsigned)yy >= (unsigned)H2) continue;
        for (int kx = 0; kx < 3; ++kx) {
            int xx = ox + kx - 1;
            if ((unsigned)xx >= (unsigned)W2) continue;
            size_t base = ((size_t)b * OHW + yy * W2 + xx) * 64;
            int tap = ky * 3 + kx;
#pragma unroll
            for (int c4 = 0; c4 < 16; ++c4) {
                f32x4 v = *(const f32x4*)(dec + base + c4 * 4);
#pragma unroll
                for (int j = 0; j < 4; ++j) {
                    int ci = c4 * 4 + j;
                    a0 += v[j] * wsm[ci * 9 + tap];
                    a1 += v[j] * wsm[(64 + ci) * 9 + tap];
                }
            }
        }
    }
    flow[(size_t)(b * 2 + 0) * OHW + rem] = a0;
    flow[(size_t)(b * 2 + 1) * OHW + rem] = a1;
}

// --------------------------------------------------------------- resize -----
__global__ void resize_kernel(const float* __restrict__ flow, float* __restrict__ out) {
    int idx = blockIdx.x * blockDim.x + threadIdx.x;
    int total = 4 * 2 * HO * WO;
    if (idx >= total) return;
    int ox = idx % WO;
    int oy = (idx / WO) % HO;
    int c = (idx / (WO * HO)) % 2;
    int b = idx / (WO * HO * 2);
    float sy = (oy + 0.5f) * 0.25f - 0.5f;
    float sx = (ox + 0.5f) * 0.25f - 0.5f;
    int y0 = (int)floorf(sy);
    int x0 = (int)floorf(sx);
    float fy = sy - y0;
    float fx = sx - x0;
    int y0c = min(max(y0, 0), H2 - 1);
    int y1c = min(max(y0 + 1, 0), H2 - 1);
    int x0c = min(max(x0, 0), W2 - 1);
    int x1c = min(max(x0 + 1, 0), W2 - 1);
    const float* fb = flow + (size_t)(b * 2 + c) * OHW;
    float v00 = fb[y0c * W2 + x0c];
    float v01 = fb[y0c * W2 + x1c];
    float v10 = fb[y1c * W2 + x0c];
    float v11 = fb[y1c * W2 + x1c];
    float v = (1.f - fy) * ((1.f - fx) * v00 + fx * v01)
            + fy * ((1.f - fx) * v10 + fx * v11);
    out[idx] = v * 4.0f;
}

// =================================================================== host ===
extern "C" void kernel_launch(void* const* d_in, const int* in_sizes, int n_in,
                              void* d_out, int out_size, void* d_ws, size_t ws_size,
                              hipStream_t stream) {
    const float* x1   = (const float*)d_in[0];
    const float* x2   = (const float*)d_in[1];
    const float* xt   = (const float*)d_in[2];
    const float* gln  = (const float*)d_in[3];
    const float* bln  = (const float*)d_in[4];
    const float* w0   = (const float*)d_in[5];
    const float* b0   = (const float*)d_in[6];
    const float* wr1  = (const float*)d_in[7];
    const float* br1  = (const float*)d_in[8];
    const float* wr2  = (const float*)d_in[9];
    const float* br2  = (const float*)d_in[10];
    const float* w2   = (const float*)d_in[11];
    const float* b2   = (const float*)d_in[12];
    const float* w3   = (const float*)d_in[13];
    const float* b3   = (const float*)d_in[14];
    const float* wdec = (const float*)d_in[15];
    const float* bdec = (const float*)d_in[16];
    const float* wf   = (const float*)d_in[17];
    const float* bfv  = (const float*)d_in[18];
    float* out = (float*)d_out;

    char* ws = (char*)d_ws;
    ushort* x1c   = (ushort*)(ws + 1048576);
    ushort* x2c   = (ushort*)(ws + 1048576 + 31457280);
    ushort* X0hi  = (ushort*)(ws + 67108864);
    ushort* X0lo  = (ushort*)(ws + 106430464);
    const size_t P = 7864320;
    ushort* y0hi = (ushort*)(ws + 1048576 + 0 * P);
    ushort* y0lo = (ushort*)(ws + 1048576 + 1 * P);
    ushort* t1hi = (ushort*)(ws + 1048576 + 2 * P);
    ushort* t1lo = (ushort*)(ws + 1048576 + 3 * P);
    ushort* t2hi = (ushort*)(ws + 1048576 + 4 * P);
    ushort* t2lo = (ushort*)(ws + 1048576 + 5 * P);
    float*  dec  = (float*)(ws + 67108864);      // 62,914,560 B (f32)
    float*  flowb = (float*)(ws + 130023424);
    char* wp = ws + 146800640;
    ushort* W0hi  = (ushort*)(wp);             ushort* W0lo  = (ushort*)(wp + 368640);
    ushort* WR1hi = (ushort*)(wp + 737280);    ushort* WR1lo = (ushort*)(wp + 737280 + 73728);
    ushort* WR2hi = (ushort*)(wp + 884736);    ushort* WR2lo = (ushort*)(wp + 884736 + 73728);
    ushort* W2hi  = (ushort*)(wp + 1032192);   ushort* W2lo  = (ushort*)(wp + 1032192 + 73728);
    ushort* W3hi  = (ushort*)(wp + 1179648);   ushort* W3lo  = (ushort*)(wp + 1179648 + 73728);
    ushort* WDhi  = (ushort*)(wp + 1327104);   ushort* WDlo  = (ushort*)(wp + 1327104 + 73728);

    pack_w_kernel<<<90, 256, 0, stream>>>(w0, 305, 10, 0, W0hi, W0lo);
    pack_w_kernel<<<18, 256, 0, stream>>>(wr1, 64, 2, 0, WR1hi, WR1lo);
    pack_w_kernel<<<18, 256, 0, stream>>>(wr2, 64, 2, 0, WR2hi, WR2lo);
    pack_w_kernel<<<18, 256, 0, stream>>>(w2, 64, 2, 0, W2hi, W2lo);
    pack_w_kernel<<<18, 256, 0, stream>>>(w3, 64, 2, 0, W3hi, W3lo);
    pack_w_kernel<<<18, 256, 0, stream>>>(wdec, 64, 2, 1, WDhi, WDlo);

    normpack_kernel<<<dim3(480, 3, 4), 256, 0, stream>>>(
        x1, x2, xt, gln, bln, x1c, x2c, X0hi, X0lo);
    corr_mfma_kernel<<<960, 256, 0, stream>>>(x1c, x2c, X0hi, X0lo);

    conv_lds_t<10><<<480, 256, 0, stream>>>(X0hi, X0lo, W0hi, b0,
        y0hi, y0lo, nullptr, nullptr, 0.f, 0, 0);
    conv_lds_t<2><<<480, 256, 0, stream>>>(y0hi, y0lo, WR1hi, br1,
        t1hi, t1lo, nullptr, nullptr, 0.1f, 1, 0);
    conv_lds_t<2><<<480, 256, 0, stream>>>(t1hi, t1lo, WR2hi, br2,
        t2hi, t2lo, y0hi, y0lo, 0.1f, 1, 1);
    conv_lds_t<2><<<480, 256, 0, stream>>>(t2hi, t2lo, W2hi, b2,
        t1hi, t1lo, nullptr, nullptr, 0.2f, 1, 0);
    conv_lds_t<2><<<480, 256, 0, stream>>>(t1hi, t1lo, W3hi, b3,
        t2hi, t2lo, nullptr, nullptr, 0.2f, 1, 0);
    deconv_fused_kernel<<<960, 256, 0, stream>>>(t2hi, t2lo, WDhi, bdec, dec);

    flow_kernel<<<960, 256, 0, stream>>>(dec, wf, bfv, flowb);
    resize_kernel<<<30720, 256, 0, stream>>>(flowb, out);

    (void)in_sizes; (void)n_in; (void)out_size; (void)ws_size;
}

// Round 8
// 446.686 us; speedup vs baseline: 1.4675x; 1.1222x over previous
//
#include <hip/hip_runtime.h>
#include <math.h>

#define HH_ 96
#define WW_ 160
#define HW 15360          // 96*160
#define NPIX 61440        // 4*HW
#define CC 256
#define C0 320            // padded conv0 Cin
#define FF 64
#define H2 192
#define W2 320
#define OHW 61440         // 192*320
#define HO 768
#define WO 1280

typedef __attribute__((ext_vector_type(8))) short short8;
typedef __attribute__((ext_vector_type(4))) float f32x4;

__device__ __forceinline__ float bf2f(ushort u) {
    union { unsigned int i; float f; } v; v.i = ((unsigned int)u) << 16; return v.f;
}
__device__ __forceinline__ ushort f2bf(float f) {
    union { float f; unsigned int i; } v; v.f = f;
    unsigned int u = v.i;
    return (ushort)((u + 0x7FFFu + ((u >> 16) & 1u)) >> 16);
}

// ---------------- fused stats + normalize/LN + NHWC bf16 pack ---------------
// LDS index: px*265 + c + (c>>5)  (+1 pad per 32ch group -> <=2-way banks)
__global__ __launch_bounds__(256) void normpack_kernel(
    const float* __restrict__ x1, const float* __restrict__ x2, const float* __restrict__ xt,
    const float* __restrict__ gam, const float* __restrict__ bet,
    ushort* __restrict__ x1c, ushort* __restrict__ x2c,
    ushort* __restrict__ Xhi) {
    __shared__ float tile[32 * 265];
    const int t = threadIdx.x;
    const int pxt = blockIdx.x, which = blockIdx.y, b = blockIdx.z;
    const float* src = (which == 0 ? x1 : which == 1 ? x2 : xt);
    src += (size_t)b * CC * HW + pxt * 32;

    {
        int px_l = t & 31, c_hi = t >> 5;
#pragma unroll 8
        for (int i = 0; i < 32; ++i) {
            int c = i * 8 + c_hi;
            tile[px_l * 265 + c + (c >> 5)] = src[(size_t)c * HW + px_l];
        }
    }
    __syncthreads();

    const int px = t >> 3, oct = t & 7;
    float s1 = 0.f, s2 = 0.f;
    {
        const float* row = &tile[px * 265 + oct * 33];
#pragma unroll
        for (int i = 0; i < 32; ++i) {
            float v = row[(i + oct * 4) & 31];
            s1 += v; s2 += v * v;
        }
    }
    s1 += __shfl_xor(s1, 1); s1 += __shfl_xor(s1, 2); s1 += __shfl_xor(s1, 4);
    s2 += __shfl_xor(s2, 1); s2 += __shfl_xor(s2, 2); s2 += __shfl_xor(s2, 4);

    const int p = b * HW + pxt * 32 + px;
    const float* row = &tile[px * 265 + oct * 33];
    if (which < 2) {
        float inv = 1.f / fmaxf(sqrtf(s2), 1e-12f);
        ushort* dst = (which == 0 ? x1c : x2c);
        size_t ob = (size_t)p * CC + oct * 32;
#pragma unroll
        for (int g = 0; g < 4; ++g) {
            short8 v;
#pragma unroll
            for (int j = 0; j < 8; ++j)
                v[j] = (short)f2bf(row[g * 8 + j] * inv);
            *(short8*)(dst + ob + g * 8) = v;
        }
    } else {
        float m = s1 * (1.f / 256.f);
        float var = fmaxf(s2 * (1.f / 256.f) - m * m, 0.f);
        float rs = rsqrtf(var + 1e-5f);
        size_t ob = (size_t)p * C0 + oct * 32;
#pragma unroll
        for (int g = 0; g < 4; ++g) {
            short8 vh;
#pragma unroll
            for (int j = 0; j < 8; ++j) {
                int c = oct * 32 + g * 8 + j;
                vh[j] = (short)f2bf((row[g * 8 + j] - m) * rs * gam[c] + bet[c]);
            }
            *(short8*)(Xhi + ob + g * 8) = vh;
        }
        short8 z = {0, 0, 0, 0, 0, 0, 0, 0};
        *(short8*)(Xhi + (size_t)p * C0 + 256 + oct * 8) = z;
    }
}

// ---------------------------------------------------------------- corr ------
__global__ __launch_bounds__(256) void corr_mfma_kernel(
    const ushort* __restrict__ x1c, const ushort* __restrict__ x2c,
    ushort* __restrict__ Xhi) {
    const int lane = threadIdx.x & 63;
    const int wv = threadIdx.x >> 6;
    const int sid = ((blockIdx.x & 7) * 120) + (blockIdx.x >> 3);   // 960 blocks
    const int b  = sid / 240;
    const int rem = sid % 240;
    const int uq = rem / 10, xt = rem % 10;
    const int u = uq * 4 + wv;
    const int x0 = xt * 16;
    const int jl = lane & 15;
    const int kg = lane >> 4;
    const short8 zero8 = {0, 0, 0, 0, 0, 0, 0, 0};

    short8 qf[8];
    {
        size_t qb = ((size_t)b * HW + u * WW_ + x0 + jl) * CC + kg * 8;
#pragma unroll
        for (int ks = 0; ks < 8; ++ks)
            qf[ks] = *(const short8*)(x1c + qb + ks * 32);
    }

    for (int dy = -3; dy <= 3; ++dy) {
        const int y = u + dy;
        if ((unsigned)y >= (unsigned)HH_) continue;
        const int w = u + 2 * dy;
        const bool rowok = (unsigned)w < (unsigned)HH_;

        f32x4 acc0 = (f32x4){0.f, 0.f, 0.f, 0.f};
        f32x4 acc1 = (f32x4){0.f, 0.f, 0.f, 0.f};
        if (rowok) {
#pragma unroll
            for (int nt = 0; nt < 2; ++nt) {
                int kx = x0 - 6 + jl + 16 * nt;
                bool ok = (unsigned)kx < (unsigned)WW_;
                int kxc = min(max(kx, 0), WW_ - 1);
                size_t kb = ((size_t)b * HW + w * WW_ + kxc) * CC + kg * 8;
#pragma unroll
                for (int ks = 0; ks < 8; ++ks) {
                    short8 bv = *(const short8*)(x2c + kb + ks * 32);
                    if (!ok) bv = zero8;
                    if (nt == 0)
                        acc0 = __builtin_amdgcn_mfma_f32_16x16x32_bf16(qf[ks], bv, acc0, 0, 0, 0);
                    else
                        acc1 = __builtin_amdgcn_mfma_f32_16x16x32_bf16(qf[ks], bv, acc1, 0, 0, 0);
                }
            }
        }
#pragma unroll
        for (int nt = 0; nt < 2; ++nt) {
            int j = jl + 16 * nt;
#pragma unroll
            for (int r = 0; r < 4; ++r) {
                int q = kg * 4 + r;
                int tt = j - q - 6;
                if (tt & 1) continue;
                int dx = tt >> 1;
                if (dx < -3 || dx > 3) continue;
                int cx = x0 + q + dx;
                if ((unsigned)cx >= (unsigned)WW_) continue;
                float v = rowok ? (nt == 0 ? acc0[r] : acc1[r]) : 0.f;
                size_t o = ((size_t)(b * HW + y * WW_ + cx)) * C0
                         + 256 + (dy + 3) * 7 + (dx + 3);
                Xhi[o] = f2bf(v);
            }
        }
    }
}

// ------------------------------------------------------------ weight pack ---
// one launch; blockIdx.y = job (0:w0 KC=10, 1..4: convs KC=2, 5: deconv KC=2)
__global__ void pack_w_all(const float* __restrict__ w0, const float* __restrict__ wr1,
                           const float* __restrict__ wr2, const float* __restrict__ w2,
                           const float* __restrict__ w3, const float* __restrict__ wdec,
                           ushort* __restrict__ W0, ushort* __restrict__ WR1,
                           ushort* __restrict__ WR2, ushort* __restrict__ W2o,
                           ushort* __restrict__ W3o, ushort* __restrict__ WD) {
    int job = blockIdx.y;
    const float* w = job == 0 ? w0 : job == 1 ? wr1 : job == 2 ? wr2
                   : job == 3 ? w2 : job == 4 ? w3 : wdec;
    ushort* dst = job == 0 ? W0 : job == 1 ? WR1 : job == 2 ? WR2
                : job == 3 ? W2o : job == 4 ? W3o : WD;
    int CinReal = job == 0 ? 305 : 64;
    int KC = job == 0 ? 10 : 2;
    int isDeconv = (job == 5);
    int gid = blockIdx.x * blockDim.x + threadIdx.x;
    int total = 9 * KC * 4 * 64;
    if (gid >= total) return;
    int lane = gid & 63;
    int nt = (gid >> 6) & 3;
    int kc = (gid >> 8) % KC;
    int slot = (gid >> 8) / KC;
    int co = nt * 16 + (lane & 15);
    int ky = slot / 3, kx = slot % 3;
    for (int j = 0; j < 8; ++j) {
        int ci = kc * 32 + (lane >> 4) * 8 + j;
        float v = 0.f;
        if (ci < CinReal) {
            if (isDeconv) v = w[((size_t)(ci * 64 + co) * 3 + (2 - ky)) * 3 + (2 - kx)];
            else          v = w[((size_t)(co * CinReal + ci) * 3 + ky) * 3 + kx];
        }
        dst[(size_t)gid * 8 + j] = f2bf(v);
    }
}

// --------------- MFMA conv core: LDS-staged, double-buffered, hi-only -------
// LDS chunk (ushort idx): buf[2] x kg[4] x row[6] x px[34] x ch[8]
//   kg stride 1640 (pad +8), buf stride 6560.
template<int KC>
__global__ __launch_bounds__(256, 4) void conv_lds_t(
    const ushort* __restrict__ Ahi,
    const ushort* __restrict__ Whi,
    const float* __restrict__ bias,
    ushort* __restrict__ Ohi,
    const ushort* __restrict__ Rhi,
    float slope, int act, int hasres) {
    constexpr int CIN = KC * 32;
    __shared__ ushort lds[2 * 6560];
    const int t = threadIdx.x;
    const int lane = t & 63;
    const int wave = t >> 6;
    const int kg = lane >> 4;
    const int jl = lane & 15;
    const short8 zero8 = {0, 0, 0, 0, 0, 0, 0, 0};

    const int sid = ((blockIdx.x & 7) * 60) + (blockIdx.x >> 3);   // 480 blocks
    const int b0 = sid / 120;
    const int rm = sid % 120;
    const int yq = rm / 5, xw = rm % 5;
    const int y0 = yq * 4;
    const int x0 = xw * 32;
    const size_t rowbase = (size_t)b0 * HW;

    f32x4 acc[2][4];
#pragma unroll
    for (int s = 0; s < 2; ++s)
#pragma unroll
        for (int nt = 0; nt < 4; ++nt)
            acc[s][nt] = (f32x4){0.f, 0.f, 0.f, 0.f};

    auto stage = [&](ushort* buf, int kc) {
#pragma unroll
        for (int i = 0; i < 4; ++i) {
            int e = t + i * 256;
            if (e < 816) {
                int kge = e & 3;
                int q = e >> 2;
                int pe = q % 34;
                int re = q / 34;
                int gy = y0 - 1 + re, gx = x0 - 1 + pe;
                bool ok = ((unsigned)gy < 96u) && ((unsigned)gx < 160u);
                short8 vh = zero8;
                if (ok) {
                    size_t ga = ((rowbase + gy * WW_ + gx) * (size_t)CIN) + kc * 32 + kge * 8;
                    vh = *(const short8*)(Ahi + ga);
                }
                *(short8*)(buf + kge * 1640 + (re * 34 + pe) * 8) = vh;
            }
        }
    };

    stage(lds, 0);

#pragma unroll 1
    for (int kc = 0; kc < KC; ++kc) {
        __syncthreads();
        if (kc + 1 < KC) stage(lds + ((kc + 1) & 1) * 6560, kc + 1);
        const ushort* bufc = lds + (kc & 1) * 6560;
#pragma unroll
        for (int tap = 0; tap < 9; ++tap) {
            const int dy = tap / 3 - 1, dx = tap % 3 - 1;
            const int abase = kg * 1640 + (wave + dy + 1) * 272 + (jl + dx + 1) * 8;
            short8 ah0 = *(const short8*)(bufc + abase);
            short8 ah1 = *(const short8*)(bufc + abase + 128);
            const ushort* wt = Whi + (size_t)(tap * KC + kc) * 2048;
#pragma unroll
            for (int nt = 0; nt < 4; ++nt) {
                short8 bh = *(const short8*)(wt + (nt * 64 + lane) * 8);
                acc[0][nt] = __builtin_amdgcn_mfma_f32_16x16x32_bf16(ah0, bh, acc[0][nt], 0, 0, 0);
                acc[1][nt] = __builtin_amdgcn_mfma_f32_16x16x32_bf16(ah1, bh, acc[1][nt], 0, 0, 0);
            }
        }
    }

#pragma unroll
    for (int s = 0; s < 2; ++s) {
#pragma unroll
        for (int r = 0; r < 4; ++r) {
            size_t pr = rowbase + (y0 + wave) * WW_ + x0 + s * 16 + kg * 4 + r;
#pragma unroll
            for (int nt = 0; nt < 4; ++nt) {
                int co = nt * 16 + jl;
                float vv = acc[s][nt][r] + bias[co];
                size_t oo = pr * 64 + co;
                if (hasres) vv += bf2f(Rhi[oo]);
                if (act) vv = vv >= 0.f ? vv : vv * slope;
                Ohi[oo] = f2bf(vv);
            }
        }
    }
}

// ------------------------------------------- fused transposed conv (4 par) --
__global__ __launch_bounds__(256, 2) void deconv_fused_kernel(
    const ushort* __restrict__ Ahi,
    const ushort* __restrict__ Whi,
    const float* __restrict__ bias,
    float* __restrict__ dec) {
    const int lane = threadIdx.x & 63;
    const int wave = threadIdx.x >> 6;
    const int kg = lane >> 4;
    const short8 zero8 = {0, 0, 0, 0, 0, 0, 0, 0};

    const int sid = ((blockIdx.x & 7) * 120) + (blockIdx.x >> 3);   // 960 blocks
    const int b0 = sid / 240;
    const int rm = sid % 240;
    const int yq = rm / 10, xh = rm % 10;
    const int y0 = yq * 4 + wave;
    const int x0 = xh * 16;
    const size_t rowbase = (size_t)b0 * HW;

    f32x4 acc[4][4];   // [parity][nt]
#pragma unroll
    for (int p = 0; p < 4; ++p)
#pragma unroll
        for (int nt = 0; nt < 4; ++nt) acc[p][nt] = (f32x4){0.f, 0.f, 0.f, 0.f};

    const int nuse[4]   = {4, 2, 2, 1};
    const int upar[4][4] = {{0, 1, 2, 3}, {1, 3, -1, -1}, {2, 3, -1, -1}, {3, -1, -1, -1}};
    const int uslt[4][4] = {{4, 3, 1, 0}, {5, 2, -1, -1}, {7, 6, -1, -1}, {8, -1, -1, -1}};

#pragma unroll
    for (int o = 0; o < 4; ++o) {
        const int ody = o >> 1, odx = o & 1;
        int yy = y0 + ody, xx = x0 + (lane & 15) + odx;
        bool v = (unsigned)yy < 96u && (unsigned)xx < 160u;
        int yyc = min(yy, 95), xxc = min(xx, 159);
        size_t a = (rowbase + yyc * WW_ + xxc) * 64 + kg * 8;
#pragma unroll
        for (int kc = 0; kc < 2; ++kc) {
            short8 ah = *(const short8*)(Ahi + a + kc * 32);
            if (!v) ah = zero8;
#pragma unroll
            for (int u = 0; u < 4; ++u) {
                if (u >= nuse[o]) break;
                int par = upar[o][u], slot = uslt[o][u];
#pragma unroll
                for (int nt = 0; nt < 4; ++nt) {
                    short8 bh = *(const short8*)(Whi + ((size_t)slot * 2 + kc) * 2048
                                                 + ((size_t)nt * 64 + lane) * 8);
                    acc[par][nt] = __builtin_amdgcn_mfma_f32_16x16x32_bf16(ah, bh, acc[par][nt], 0, 0, 0);
                }
            }
        }
    }

#pragma unroll
    for (int r = 0; r < 4; ++r) {
        int x2 = x0 + kg * 4 + r;
#pragma unroll
        for (int par = 0; par < 4; ++par) {
            int py = par >> 1, px = par & 1;
            size_t po = ((size_t)b0 * H2 + 2 * y0 + py) * W2 + 2 * x2 + px;
#pragma unroll
            for (int nt = 0; nt < 4; ++nt) {
                int co = nt * 16 + (lane & 15);
                dec[po * 64 + co] = acc[par][nt][r] + bias[co];
            }
        }
    }
}

// ---------------------------------------------------------------- flow ------
__global__ __launch_bounds__(256) void flow_kernel(const float* __restrict__ dec,
                                                   const float* __restrict__ wf,
                                                   const float* __restrict__ bf2v,
                                                   float* __restrict__ flow) {
    __shared__ float wsm[1152];
    for (int i = threadIdx.x; i < 1152; i += 256) wsm[i] = wf[i];
    __syncthreads();
    int fid = ((blockIdx.x & 7) * 120) + (blockIdx.x >> 3);   // 960 blocks
    int p = fid * 256 + threadIdx.x;
    if (p >= 4 * OHW) return;
    int b = p / OHW, rem = p % OHW, oy = rem / W2, ox = rem % W2;
    float a0 = bf2v[0], a1 = bf2v[1];
    for (int ky = 0; ky < 3; ++ky) {
        int yy = oy + ky - 1;
        if ((unsigned)yy >= (unsigned)H2) continue;
        for (int kx = 0; kx < 3; ++kx) {
            int xx = ox + kx - 1;
            if ((unsigned)xx >= (unsigned)W2) continue;
            size_t base = ((size_t)b * OHW + yy * W2 + xx) * 64;
            int tap = ky * 3 + kx;
#pragma unroll
            for (int c4 = 0; c4 < 16; ++c4) {
                f32x4 v = *(const f32x4*)(dec + base + c4 * 4);
#pragma unroll
                for (int j = 0; j < 4; ++j) {
                    int ci = c4 * 4 + j;
                    a0 += v[j] * wsm[ci * 9 + tap];
                    a1 += v[j] * wsm[(64 + ci) * 9 + tap];
                }
            }
        }
    }
    flow[(size_t)(b * 2 + 0) * OHW + rem] = a0;
    flow[(size_t)(b * 2 + 1) * OHW + rem] = a1;
}

// --------------------------------------------------------------- resize -----
__global__ void resize_kernel(const float* __restrict__ flow, float* __restrict__ out) {
    int idx = blockIdx.x * blockDim.x + threadIdx.x;
    int total = 4 * 2 * HO * WO;
    if (idx >= total) return;
    int ox = idx % WO;
    int oy = (idx / WO) % HO;
    int c = (idx / (WO * HO)) % 2;
    int b = idx / (WO * HO * 2);
    float sy = (oy + 0.5f) * 0.25f - 0.5f;
    float sx = (ox + 0.5f) * 0.25f - 0.5f;
    int y0 = (int)floorf(sy);
    int x0 = (int)floorf(sx);
    float fy = sy - y0;
    float fx = sx - x0;
    int y0c = min(max(y0, 0), H2 - 1);
    int y1c = min(max(y0 + 1, 0), H2 - 1);
    int x0c = min(max(x0, 0), W2 - 1);
    int x1c = min(max(x0 + 1, 0), W2 - 1);
    const float* fb = flow + (size_t)(b * 2 + c) * OHW;
    float v00 = fb[y0c * W2 + x0c];
    float v01 = fb[y0c * W2 + x1c];
    float v10 = fb[y1c * W2 + x0c];
    float v11 = fb[y1c * W2 + x1c];
    float v = (1.f - fy) * ((1.f - fx) * v00 + fx * v01)
            + fy * ((1.f - fx) * v10 + fx * v11);
    out[idx] = v * 4.0f;
}

// =================================================================== host ===
extern "C" void kernel_launch(void* const* d_in, const int* in_sizes, int n_in,
                              void* d_out, int out_size, void* d_ws, size_t ws_size,
                              hipStream_t stream) {
    const float* x1   = (const float*)d_in[0];
    const float* x2   = (const float*)d_in[1];
    const float* xt   = (const float*)d_in[2];
    const float* gln  = (const float*)d_in[3];
    const float* bln  = (const float*)d_in[4];
    const float* w0   = (const float*)d_in[5];
    const float* b0   = (const float*)d_in[6];
    const float* wr1  = (const float*)d_in[7];
    const float* br1  = (const float*)d_in[8];
    const float* wr2  = (const float*)d_in[9];
    const float* br2  = (const float*)d_in[10];
    const float* w2   = (const float*)d_in[11];
    const float* b2   = (const float*)d_in[12];
    const float* w3   = (const float*)d_in[13];
    const float* b3   = (const float*)d_in[14];
    const float* wdec = (const float*)d_in[15];
    const float* bdec = (const float*)d_in[16];
    const float* wf   = (const float*)d_in[17];
    const float* bfv  = (const float*)d_in[18];
    float* out = (float*)d_out;

    char* ws = (char*)d_ws;
    ushort* x1c  = (ushort*)(ws + 0);               // 31,457,280
    ushort* x2c  = (ushort*)(ws + 31457280);        // 31,457,280
    ushort* X0hi = (ushort*)(ws + 62914560);        // 39,321,600
    ushort* y0hi = (ushort*)(ws + 102236160);       //  7,864,320
    ushort* t1hi = (ushort*)(ws + 110100480);
    ushort* t2hi = (ushort*)(ws + 117964800);
    float*  dec  = (float*)(ws + 0);                // reuse x1c/x2c after corr
    float*  flowb = (float*)(ws + 62914560);        // reuse X0 after conv0
    char* wp = ws + 125829120;
    ushort* W0hi  = (ushort*)(wp);                  // 368,640
    ushort* WR1hi = (ushort*)(wp + 368640);
    ushort* WR2hi = (ushort*)(wp + 442368);
    ushort* W2hi  = (ushort*)(wp + 516096);
    ushort* W3hi  = (ushort*)(wp + 589824);
    ushort* WDhi  = (ushort*)(wp + 663552);         // ends ~126.6 MB

    pack_w_all<<<dim3(90, 6), 256, 0, stream>>>(w0, wr1, wr2, w2, w3, wdec,
        W0hi, WR1hi, WR2hi, W2hi, W3hi, WDhi);

    normpack_kernel<<<dim3(480, 3, 4), 256, 0, stream>>>(
        x1, x2, xt, gln, bln, x1c, x2c, X0hi);
    corr_mfma_kernel<<<960, 256, 0, stream>>>(x1c, x2c, X0hi);

    conv_lds_t<10><<<480, 256, 0, stream>>>(X0hi, W0hi, b0, y0hi, nullptr, 0.f, 0, 0);
    conv_lds_t<2><<<480, 256, 0, stream>>>(y0hi, WR1hi, br1, t1hi, nullptr, 0.1f, 1, 0);
    conv_lds_t<2><<<480, 256, 0, stream>>>(t1hi, WR2hi, br2, t2hi, y0hi, 0.1f, 1, 1);
    conv_lds_t<2><<<480, 256, 0, stream>>>(t2hi, W2hi, b2, t1hi, nullptr, 0.2f, 1, 0);
    conv_lds_t<2><<<480, 256, 0, stream>>>(t1hi, W3hi, b3, t2hi, nullptr, 0.2f, 1, 0);
    deconv_fused_kernel<<<960, 256, 0, stream>>>(t2hi, WDhi, bdec, dec);

    flow_kernel<<<960, 256, 0, stream>>>(dec, wf, bfv, flowb);
    resize_kernel<<<30720, 256, 0, stream>>>(flowb, out);

    (void)in_sizes; (void)n_in; (void)out_size; (void)ws_size;
}

// Round 9
// 369.104 us; speedup vs baseline: 1.7760x; 1.2102x over previous
//
#include <hip/hip_runtime.h>
#include <math.h>

#define HH_ 96
#define WW_ 160
#define HW 15360          // 96*160
#define NPIX 61440        // 4*HW
#define CC 256
#define C0 320            // padded conv0 Cin
#define FF 64
#define H2 192
#define W2 320
#define OHW 61440         // 192*320
#define HO 768
#define WO 1280

typedef __attribute__((ext_vector_type(8))) short short8;
typedef __attribute__((ext_vector_type(4))) float f32x4;

__device__ __forceinline__ float bf2f(ushort u) {
    union { unsigned int i; float f; } v; v.i = ((unsigned int)u) << 16; return v.f;
}
__device__ __forceinline__ ushort f2bf(float f) {
    union { float f; unsigned int i; } v; v.f = f;
    unsigned int u = v.i;
    return (ushort)((u + 0x7FFFu + ((u >> 16) & 1u)) >> 16);
}

// ---------------- fused stats + normalize/LN + NHWC bf16 pack ---------------
// LDS index: px*265 + c + (c>>5)  (+1 pad per 32ch group -> <=2-way banks)
__global__ __launch_bounds__(256) void normpack_kernel(
    const float* __restrict__ x1, const float* __restrict__ x2, const float* __restrict__ xt,
    const float* __restrict__ gam, const float* __restrict__ bet,
    ushort* __restrict__ x1c, ushort* __restrict__ x2c,
    ushort* __restrict__ Xhi) {
    __shared__ float tile[32 * 265];
    const int t = threadIdx.x;
    const int pxt = blockIdx.x, which = blockIdx.y, b = blockIdx.z;
    const float* src = (which == 0 ? x1 : which == 1 ? x2 : xt);
    src += (size_t)b * CC * HW + pxt * 32;

    {
        int px_l = t & 31, c_hi = t >> 5;
#pragma unroll 8
        for (int i = 0; i < 32; ++i) {
            int c = i * 8 + c_hi;
            tile[px_l * 265 + c + (c >> 5)] = src[(size_t)c * HW + px_l];
        }
    }
    __syncthreads();

    const int px = t >> 3, oct = t & 7;
    float s1 = 0.f, s2 = 0.f;
    {
        const float* row = &tile[px * 265 + oct * 33];
#pragma unroll
        for (int i = 0; i < 32; ++i) {
            float v = row[(i + oct * 4) & 31];
            s1 += v; s2 += v * v;
        }
    }
    s1 += __shfl_xor(s1, 1); s1 += __shfl_xor(s1, 2); s1 += __shfl_xor(s1, 4);
    s2 += __shfl_xor(s2, 1); s2 += __shfl_xor(s2, 2); s2 += __shfl_xor(s2, 4);

    const int p = b * HW + pxt * 32 + px;
    const float* row = &tile[px * 265 + oct * 33];
    if (which < 2) {
        float inv = 1.f / fmaxf(sqrtf(s2), 1e-12f);
        ushort* dst = (which == 0 ? x1c : x2c);
        size_t ob = (size_t)p * CC + oct * 32;
#pragma unroll
        for (int g = 0; g < 4; ++g) {
            short8 v;
#pragma unroll
            for (int j = 0; j < 8; ++j)
                v[j] = (short)f2bf(row[g * 8 + j] * inv);
            *(short8*)(dst + ob + g * 8) = v;
        }
    } else {
        float m = s1 * (1.f / 256.f);
        float var = fmaxf(s2 * (1.f / 256.f) - m * m, 0.f);
        float rs = rsqrtf(var + 1e-5f);
        size_t ob = (size_t)p * C0 + oct * 32;
#pragma unroll
        for (int g = 0; g < 4; ++g) {
            short8 vh;
#pragma unroll
            for (int j = 0; j < 8; ++j) {
                int c = oct * 32 + g * 8 + j;
                vh[j] = (short)f2bf((row[g * 8 + j] - m) * rs * gam[c] + bet[c]);
            }
            *(short8*)(Xhi + ob + g * 8) = vh;
        }
        short8 z = {0, 0, 0, 0, 0, 0, 0, 0};
        *(short8*)(Xhi + (size_t)p * C0 + 256 + oct * 8) = z;
    }
}

// ---------------------------------------------------------------- corr ------
__global__ __launch_bounds__(256) void corr_mfma_kernel(
    const ushort* __restrict__ x1c, const ushort* __restrict__ x2c,
    ushort* __restrict__ Xhi) {
    const int lane = threadIdx.x & 63;
    const int wv = threadIdx.x >> 6;
    const int sid = ((blockIdx.x & 7) * 120) + (blockIdx.x >> 3);   // 960 blocks
    const int b  = sid / 240;
    const int rem = sid % 240;
    const int uq = rem / 10, xt = rem % 10;
    const int u = uq * 4 + wv;
    const int x0 = xt * 16;
    const int jl = lane & 15;
    const int kg = lane >> 4;
    const short8 zero8 = {0, 0, 0, 0, 0, 0, 0, 0};

    short8 qf[8];
    {
        size_t qb = ((size_t)b * HW + u * WW_ + x0 + jl) * CC + kg * 8;
#pragma unroll
        for (int ks = 0; ks < 8; ++ks)
            qf[ks] = *(const short8*)(x1c + qb + ks * 32);
    }

    for (int dy = -3; dy <= 3; ++dy) {
        const int y = u + dy;
        if ((unsigned)y >= (unsigned)HH_) continue;
        const int w = u + 2 * dy;
        const bool rowok = (unsigned)w < (unsigned)HH_;

        f32x4 acc0 = (f32x4){0.f, 0.f, 0.f, 0.f};
        f32x4 acc1 = (f32x4){0.f, 0.f, 0.f, 0.f};
        if (rowok) {
#pragma unroll
            for (int nt = 0; nt < 2; ++nt) {
                int kx = x0 - 6 + jl + 16 * nt;
                bool ok = (unsigned)kx < (unsigned)WW_;
                int kxc = min(max(kx, 0), WW_ - 1);
                size_t kb = ((size_t)b * HW + w * WW_ + kxc) * CC + kg * 8;
#pragma unroll
                for (int ks = 0; ks < 8; ++ks) {
                    short8 bv = *(const short8*)(x2c + kb + ks * 32);
                    if (!ok) bv = zero8;
                    if (nt == 0)
                        acc0 = __builtin_amdgcn_mfma_f32_16x16x32_bf16(qf[ks], bv, acc0, 0, 0, 0);
                    else
                        acc1 = __builtin_amdgcn_mfma_f32_16x16x32_bf16(qf[ks], bv, acc1, 0, 0, 0);
                }
            }
        }
#pragma unroll
        for (int nt = 0; nt < 2; ++nt) {
            int j = jl + 16 * nt;
#pragma unroll
            for (int r = 0; r < 4; ++r) {
                int q = kg * 4 + r;
                int tt = j - q - 6;
                if (tt & 1) continue;
                int dx = tt >> 1;
                if (dx < -3 || dx > 3) continue;
                int cx = x0 + q + dx;
                if ((unsigned)cx >= (unsigned)WW_) continue;
                float v = rowok ? (nt == 0 ? acc0[r] : acc1[r]) : 0.f;
                size_t o = ((size_t)(b * HW + y * WW_ + cx)) * C0
                         + 256 + (dy + 3) * 7 + (dx + 3);
                Xhi[o] = f2bf(v);
            }
        }
    }
}

// ------------------------------------------------------------ weight pack ---
__global__ void pack_w_all(const float* __restrict__ w0, const float* __restrict__ wr1,
                           const float* __restrict__ wr2, const float* __restrict__ w2,
                           const float* __restrict__ w3, const float* __restrict__ wdec,
                           ushort* __restrict__ W0, ushort* __restrict__ WR1,
                           ushort* __restrict__ WR2, ushort* __restrict__ W2o,
                           ushort* __restrict__ W3o, ushort* __restrict__ WD) {
    int job = blockIdx.y;
    const float* w = job == 0 ? w0 : job == 1 ? wr1 : job == 2 ? wr2
                   : job == 3 ? w2 : job == 4 ? w3 : wdec;
    ushort* dst = job == 0 ? W0 : job == 1 ? WR1 : job == 2 ? WR2
                : job == 3 ? W2o : job == 4 ? W3o : WD;
    int CinReal = job == 0 ? 305 : 64;
    int KC = job == 0 ? 10 : 2;
    int isDeconv = (job == 5);
    int gid = blockIdx.x * blockDim.x + threadIdx.x;
    int total = 9 * KC * 4 * 64;
    if (gid >= total) return;
    int lane = gid & 63;
    int nt = (gid >> 6) & 3;
    int kc = (gid >> 8) % KC;
    int slot = (gid >> 8) / KC;
    int co = nt * 16 + (lane & 15);
    int ky = slot / 3, kx = slot % 3;
    for (int j = 0; j < 8; ++j) {
        int ci = kc * 32 + (lane >> 4) * 8 + j;
        float v = 0.f;
        if (ci < CinReal) {
            if (isDeconv) v = w[((size_t)(ci * 64 + co) * 3 + (2 - ky)) * 3 + (2 - kx)];
            else          v = w[((size_t)(co * CinReal + ci) * 3 + ky) * 3 + kx];
        }
        dst[(size_t)gid * 8 + j] = f2bf(v);
    }
}

// --------------- MFMA conv core: LDS-staged, dbuf, hi-only, M=64 tile -------
// Block: 4 waves, tile 4 rows x 16 px; wave computes 16px x 64ch.
// LDS chunk (ushort): kg[4] x row[6] x px[18] x ch[8]; kg stride 872 (pad+8).
template<int KC>
__global__ __launch_bounds__(256, 4) void conv_lds_t(
    const ushort* __restrict__ Ahi,
    const ushort* __restrict__ Whi,
    const float* __restrict__ bias,
    ushort* __restrict__ Ohi,
    const ushort* __restrict__ Rhi,
    float slope, int act, int hasres) {
    constexpr int CIN = KC * 32;
    __shared__ ushort lds[2 * 3488];
    const int t = threadIdx.x;
    const int lane = t & 63;
    const int wave = t >> 6;
    const int kg = lane >> 4;
    const int jl = lane & 15;
    const short8 zero8 = {0, 0, 0, 0, 0, 0, 0, 0};

    const int sid = ((blockIdx.x & 7) * 120) + (blockIdx.x >> 3);   // 960 blocks
    const int b0 = sid / 240;
    const int rm = sid % 240;
    const int yq = rm / 10, xw = rm % 10;
    const int y0 = yq * 4;
    const int x0 = xw * 16;
    const size_t rowbase = (size_t)b0 * HW;

    f32x4 acc[4];
#pragma unroll
    for (int nt = 0; nt < 4; ++nt) acc[nt] = (f32x4){0.f, 0.f, 0.f, 0.f};

    // stage: 432 = 6 rows x 18 px x 4 kg 16B-loads
    auto stage = [&](ushort* buf, int kc) {
#pragma unroll
        for (int i = 0; i < 2; ++i) {
            int e = t + i * 256;
            if (e < 432) {
                int kge = e & 3;
                int q = e >> 2;
                int pe = q % 18;
                int re = q / 18;
                int gy = y0 - 1 + re, gx = x0 - 1 + pe;
                bool ok = ((unsigned)gy < 96u) && ((unsigned)gx < 160u);
                short8 vh = zero8;
                if (ok) {
                    size_t ga = ((rowbase + gy * WW_ + gx) * (size_t)CIN) + kc * 32 + kge * 8;
                    vh = *(const short8*)(Ahi + ga);
                }
                *(short8*)(buf + kge * 872 + (re * 18 + pe) * 8) = vh;
            }
        }
    };

    stage(lds, 0);

#pragma unroll 1
    for (int kc = 0; kc < KC; ++kc) {
        __syncthreads();
        if (kc + 1 < KC) stage(lds + ((kc + 1) & 1) * 3488, kc + 1);
        const ushort* bufc = lds + (kc & 1) * 3488;
#pragma unroll
        for (int tap = 0; tap < 9; ++tap) {
            const int dy = tap / 3 - 1, dx = tap % 3 - 1;
            const int abase = kg * 872 + (wave + dy + 1) * 144 + (jl + dx + 1) * 8;
            short8 ah = *(const short8*)(bufc + abase);
            const ushort* wt = Whi + (size_t)(tap * KC + kc) * 2048;
#pragma unroll
            for (int nt = 0; nt < 4; ++nt) {
                short8 bh = *(const short8*)(wt + (nt * 64 + lane) * 8);
                acc[nt] = __builtin_amdgcn_mfma_f32_16x16x32_bf16(ah, bh, acc[nt], 0, 0, 0);
            }
        }
    }

#pragma unroll
    for (int r = 0; r < 4; ++r) {
        size_t pr = rowbase + (y0 + wave) * WW_ + x0 + kg * 4 + r;
#pragma unroll
        for (int nt = 0; nt < 4; ++nt) {
            int co = nt * 16 + jl;
            float vv = acc[nt][r] + bias[co];
            size_t oo = pr * 64 + co;
            if (hasres) vv += bf2f(Rhi[oo]);
            if (act) vv = vv >= 0.f ? vv : vv * slope;
            Ohi[oo] = f2bf(vv);
        }
    }
}

// ------------------------------------------- fused transposed conv (4 par) --
__global__ __launch_bounds__(256, 2) void deconv_fused_kernel(
    const ushort* __restrict__ Ahi,
    const ushort* __restrict__ Whi,
    const float* __restrict__ bias,
    float* __restrict__ dec) {
    const int lane = threadIdx.x & 63;
    const int wave = threadIdx.x >> 6;
    const int kg = lane >> 4;
    const short8 zero8 = {0, 0, 0, 0, 0, 0, 0, 0};

    const int sid = ((blockIdx.x & 7) * 120) + (blockIdx.x >> 3);   // 960 blocks
    const int b0 = sid / 240;
    const int rm = sid % 240;
    const int yq = rm / 10, xh = rm % 10;
    const int y0 = yq * 4 + wave;
    const int x0 = xh * 16;
    const size_t rowbase = (size_t)b0 * HW;

    f32x4 acc[4][4];   // [parity][nt]
#pragma unroll
    for (int p = 0; p < 4; ++p)
#pragma unroll
        for (int nt = 0; nt < 4; ++nt) acc[p][nt] = (f32x4){0.f, 0.f, 0.f, 0.f};

    const int nuse[4]   = {4, 2, 2, 1};
    const int upar[4][4] = {{0, 1, 2, 3}, {1, 3, -1, -1}, {2, 3, -1, -1}, {3, -1, -1, -1}};
    const int uslt[4][4] = {{4, 3, 1, 0}, {5, 2, -1, -1}, {7, 6, -1, -1}, {8, -1, -1, -1}};

#pragma unroll
    for (int o = 0; o < 4; ++o) {
        const int ody = o >> 1, odx = o & 1;
        int yy = y0 + ody, xx = x0 + (lane & 15) + odx;
        bool v = (unsigned)yy < 96u && (unsigned)xx < 160u;
        int yyc = min(yy, 95), xxc = min(xx, 159);
        size_t a = (rowbase + yyc * WW_ + xxc) * 64 + kg * 8;
#pragma unroll
        for (int kc = 0; kc < 2; ++kc) {
            short8 ah = *(const short8*)(Ahi + a + kc * 32);
            if (!v) ah = zero8;
#pragma unroll
            for (int u = 0; u < 4; ++u) {
                if (u >= nuse[o]) break;
                int par = upar[o][u], slot = uslt[o][u];
#pragma unroll
                for (int nt = 0; nt < 4; ++nt) {
                    short8 bh = *(const short8*)(Whi + ((size_t)slot * 2 + kc) * 2048
                                                 + ((size_t)nt * 64 + lane) * 8);
                    acc[par][nt] = __builtin_amdgcn_mfma_f32_16x16x32_bf16(ah, bh, acc[par][nt], 0, 0, 0);
                }
            }
        }
    }

#pragma unroll
    for (int r = 0; r < 4; ++r) {
        int x2 = x0 + kg * 4 + r;
#pragma unroll
        for (int par = 0; par < 4; ++par) {
            int py = par >> 1, px = par & 1;
            size_t po = ((size_t)b0 * H2 + 2 * y0 + py) * W2 + 2 * x2 + px;
#pragma unroll
            for (int nt = 0; nt < 4; ++nt) {
                int co = nt * 16 + (lane & 15);
                dec[po * 64 + co] = acc[par][nt][r] + bias[co];
            }
        }
    }
}

// ---------------------------------------------------------------- flow ------
__global__ __launch_bounds__(256) void flow_kernel(const float* __restrict__ dec,
                                                   const float* __restrict__ wf,
                                                   const float* __restrict__ bf2v,
                                                   float* __restrict__ flow) {
    __shared__ float wsm[1152];
    for (int i = threadIdx.x; i < 1152; i += 256) wsm[i] = wf[i];
    __syncthreads();
    int fid = ((blockIdx.x & 7) * 120) + (blockIdx.x >> 3);   // 960 blocks
    int p = fid * 256 + threadIdx.x;
    if (p >= 4 * OHW) return;
    int b = p / OHW, rem = p % OHW, oy = rem / W2, ox = rem % W2;
    float a0 = bf2v[0], a1 = bf2v[1];
    for (int ky = 0; ky < 3; ++ky) {
        int yy = oy + ky - 1;
        if ((unsigned)yy >= (unsigned)H2) continue;
        for (int kx = 0; kx < 3; ++kx) {
            int xx = ox + kx - 1;
            if ((unsigned)xx >= (unsigned)W2) continue;
            size_t base = ((size_t)b * OHW + yy * W2 + xx) * 64;
            int tap = ky * 3 + kx;
#pragma unroll
            for (int c4 = 0; c4 < 16; ++c4) {
                f32x4 v = *(const f32x4*)(dec + base + c4 * 4);
#pragma unroll
                for (int j = 0; j < 4; ++j) {
                    int ci = c4 * 4 + j;
                    a0 += v[j] * wsm[ci * 9 + tap];
                    a1 += v[j] * wsm[(64 + ci) * 9 + tap];
                }
            }
        }
    }
    flow[(size_t)(b * 2 + 0) * OHW + rem] = a0;
    flow[(size_t)(b * 2 + 1) * OHW + rem] = a1;
}

// --------------------------------------------------------------- resize -----
__global__ void resize_kernel(const float* __restrict__ flow, float* __restrict__ out) {
    int idx = blockIdx.x * blockDim.x + threadIdx.x;
    int total = 4 * 2 * HO * WO;
    if (idx >= total) return;
    int ox = idx % WO;
    int oy = (idx / WO) % HO;
    int c = (idx / (WO * HO)) % 2;
    int b = idx / (WO * HO * 2);
    float sy = (oy + 0.5f) * 0.25f - 0.5f;
    float sx = (ox + 0.5f) * 0.25f - 0.5f;
    int y0 = (int)floorf(sy);
    int x0 = (int)floorf(sx);
    float fy = sy - y0;
    float fx = sx - x0;
    int y0c = min(max(y0, 0), H2 - 1);
    int y1c = min(max(y0 + 1, 0), H2 - 1);
    int x0c = min(max(x0, 0), W2 - 1);
    int x1c = min(max(x0 + 1, 0), W2 - 1);
    const float* fb = flow + (size_t)(b * 2 + c) * OHW;
    float v00 = fb[y0c * W2 + x0c];
    float v01 = fb[y0c * W2 + x1c];
    float v10 = fb[y1c * W2 + x0c];
    float v11 = fb[y1c * W2 + x1c];
    float v = (1.f - fy) * ((1.f - fx) * v00 + fx * v01)
            + fy * ((1.f - fx) * v10 + fx * v11);
    out[idx] = v * 4.0f;
}

// =================================================================== host ===
extern "C" void kernel_launch(void* const* d_in, const int* in_sizes, int n_in,
                              void* d_out, int out_size, void* d_ws, size_t ws_size,
                              hipStream_t stream) {
    const float* x1   = (const float*)d_in[0];
    const float* x2   = (const float*)d_in[1];
    const float* xt   = (const float*)d_in[2];
    const float* gln  = (const float*)d_in[3];
    const float* bln  = (const float*)d_in[4];
    const float* w0   = (const float*)d_in[5];
    const float* b0   = (const float*)d_in[6];
    const float* wr1  = (const float*)d_in[7];
    const float* br1  = (const float*)d_in[8];
    const float* wr2  = (const float*)d_in[9];
    const float* br2  = (const float*)d_in[10];
    const float* w2   = (const float*)d_in[11];
    const float* b2   = (const float*)d_in[12];
    const float* w3   = (const float*)d_in[13];
    const float* b3   = (const float*)d_in[14];
    const float* wdec = (const float*)d_in[15];
    const float* bdec = (const float*)d_in[16];
    const float* wf   = (const float*)d_in[17];
    const float* bfv  = (const float*)d_in[18];
    float* out = (float*)d_out;

    char* ws = (char*)d_ws;
    ushort* x1c  = (ushort*)(ws + 0);               // 31,457,280
    ushort* x2c  = (ushort*)(ws + 31457280);        // 31,457,280
    ushort* X0hi = (ushort*)(ws + 62914560);        // 39,321,600
    ushort* y0hi = (ushort*)(ws + 102236160);       //  7,864,320
    ushort* t1hi = (ushort*)(ws + 110100480);
    ushort* t2hi = (ushort*)(ws + 117964800);
    float*  dec  = (float*)(ws + 0);                // reuse x1c/x2c after corr
    float*  flowb = (float*)(ws + 62914560);        // reuse X0 after conv0
    char* wp = ws + 125829120;
    ushort* W0hi  = (ushort*)(wp);                  // 368,640
    ushort* WR1hi = (ushort*)(wp + 368640);
    ushort* WR2hi = (ushort*)(wp + 442368);
    ushort* W2hi  = (ushort*)(wp + 516096);
    ushort* W3hi  = (ushort*)(wp + 589824);
    ushort* WDhi  = (ushort*)(wp + 663552);

    pack_w_all<<<dim3(90, 6), 256, 0, stream>>>(w0, wr1, wr2, w2, w3, wdec,
        W0hi, WR1hi, WR2hi, W2hi, W3hi, WDhi);

    normpack_kernel<<<dim3(480, 3, 4), 256, 0, stream>>>(
        x1, x2, xt, gln, bln, x1c, x2c, X0hi);
    corr_mfma_kernel<<<960, 256, 0, stream>>>(x1c, x2c, X0hi);

    conv_lds_t<10><<<960, 256, 0, stream>>>(X0hi, W0hi, b0, y0hi, nullptr, 0.f, 0, 0);
    conv_lds_t<2><<<960, 256, 0, stream>>>(y0hi, WR1hi, br1, t1hi, nullptr, 0.1f, 1, 0);
    conv_lds_t<2><<<960, 256, 0, stream>>>(t1hi, WR2hi, br2, t2hi, y0hi, 0.1f, 1, 1);
    conv_lds_t<2><<<960, 256, 0, stream>>>(t2hi, W2hi, b2, t1hi, nullptr, 0.2f, 1, 0);
    conv_lds_t<2><<<960, 256, 0, stream>>>(t1hi, W3hi, b3, t2hi, nullptr, 0.2f, 1, 0);
    deconv_fused_kernel<<<960, 256, 0, stream>>>(t2hi, WDhi, bdec, dec);

    flow_kernel<<<960, 256, 0, stream>>>(dec, wf, bfv, flowb);
    resize_kernel<<<30720, 256, 0, stream>>>(flowb, out);

    (void)in_sizes; (void)n_in; (void)out_size; (void)ws_size;
}